// Round 14
// baseline (41.380 us; speedup 1.0000x reference)
//
#include <hip/hip_runtime.h>

#define NFEAT 40
#define EMB   64
#define ATT   32
#define NPAIR 780
#define NTILE 49
#define XH_S  72                 // fp16 x LDS stride (elems) -> 144 B rows
#define XREG  (NFEAT * XH_S)     // 2880 elems = 5760 B per batch region

// d_ws layout (u32 units): [0,800) packed pair table prtp[k*32+l15*2+half],
// [1024,2560) W-frags (24 u32/lane, lane-major), [4096,5120) per-lane f32
// consts {cb0[4],cb1[4],h0*log2e[4],h1*log2e[4]}. Total 20 KB of d_ws.
#define WS_PRT   0
#define WS_WF    1024
#define WS_CONST 4096

typedef __attribute__((ext_vector_type(8))) _Float16 f16x8;
typedef __attribute__((ext_vector_type(4))) float    f32x4;
typedef __attribute__((ext_vector_type(2))) unsigned u32x2;

template <int CTRL>
__device__ __forceinline__ float dpp_add_f(float v) {
  int t = __builtin_amdgcn_update_dpp(0, __float_as_int(v), CTRL, 0xF, 0xF, true);
  return v + __int_as_float(t);
}
__device__ __forceinline__ float rowsum16(float v) {
  v = dpp_add_f<0x128>(v);
  v = dpp_add_f<0x124>(v);
  v = dpp_add_f<0x122>(v);
  v = dpp_add_f<0x121>(v);
  return v;
}
__device__ __forceinline__ float xgroup_sum(float v) {
#if __has_builtin(__builtin_amdgcn_permlane16_swap) && __has_builtin(__builtin_amdgcn_permlane32_swap)
  {
    auto a = __builtin_amdgcn_permlane16_swap(__float_as_uint(v), __float_as_uint(v), false, false);
    v = __uint_as_float(a[0]) + __uint_as_float(a[1]);
    auto b = __builtin_amdgcn_permlane32_swap(__float_as_uint(v), __float_as_uint(v), false, false);
    v = __uint_as_float(b[0]) + __uint_as_float(b[1]);
  }
#else
  v += __shfl_xor(v, 16, 64);
  v += __shfl_xor(v, 32, 64);
#endif
  return v;
}
__device__ __forceinline__ int pair_off(int i) { return 39 * i - (i * (i - 1)) / 2; }

// ---------------- precompute kernel: fills d_ws once per launch ----------------
extern "C" __global__ __launch_bounds__(256)
void afm_pre(const float* __restrict__ Wg, const float* __restrict__ bg,
             const float* __restrict__ hg, const float* __restrict__ pg,
             unsigned* __restrict__ ws) {
  __shared__ float Wl[EMB * ATT];   // 8 KB
  const int tid = threadIdx.x;
  const float L2E = 1.4426950408889634f;

  if (blockIdx.x == 0) {            // W fragments (needs W staged in LDS)
    for (int f = tid; f < EMB * ATT / 4; f += 256)
      *(float4*)&Wl[f * 4] = ((const float4*)Wg)[f];
    __syncthreads();
    for (int o = tid; o < 1536; o += 256) {
      int lane = o / 24, rem = o % 24, frag = rem >> 2, pi = rem & 3;
      int kk = frag / 3, which = frag % 3;
      int l15 = lane & 15, hk = lane >> 4;
      unsigned out = 0;
#pragma unroll
      for (int s = 0; s < 2; s++) {
        int t = pi * 2 + s;
        int krow = kk * 32 + hk * 8 + t;
        float v = (which == 0) ? Wl[krow * ATT + l15]
                : (which == 1) ? Wl[krow * ATT + 16 + l15]
                               : ((l15 == 0) ? pg[krow] : 0.f);
        _Float16 hv = (_Float16)v;
        unsigned short bits = __builtin_bit_cast(unsigned short, hv);
        out |= (unsigned)bits << (16 * s);
      }
      ws[WS_WF + lane * 24 + rem] = out;
    }
  } else if (blockIdx.x == 1) {     // packed pair table
    for (int p = tid; p < NTILE * 16; p += 256) {
      int i = 0, j = 0;
      if (p < NPAIR) {
        i = (int)((79.0f - sqrtf(6241.0f - 8.0f * (float)p)) * 0.5f);
        if (i < 0) i = 0;
        while (pair_off(i + 1) <= p) ++i;
        while (pair_off(i) > p) --i;
        j = i + 1 + (p - pair_off(i));
      }
      int t = p >> 4, l = p & 15;
      ws[WS_PRT + (t >> 1) * 32 + l * 2 + (t & 1)] =
          (unsigned)(i * 144) | ((unsigned)(j * 144) << 16);
    }
  } else if (blockIdx.x == 2) {     // per-lane bias/h consts
    for (int o = tid; o < 1024; o += 256) {
      int lane = o >> 4, r = o & 15;
      int hk = lane >> 4, g = r >> 2, e = r & 3;
      float v;
      if (g == 0)      v = bg[hk * 4 + e];
      else if (g == 1) v = bg[16 + hk * 4 + e];
      else if (g == 2) v = hg[hk * 4 + e] * L2E;
      else             v = hg[16 + hk * 4 + e] * L2E;
      ((float*)ws)[WS_CONST + o] = v;
    }
  }
}

// ---------------- main kernel: 2 waves/block, 1 batch/wave, no barriers ----------------
extern "C" __global__ __launch_bounds__(128)
void afm_kernel(const float* __restrict__ xg, const unsigned* __restrict__ ws,
                float* __restrict__ outg, int nbatch) {
  __shared__ __align__(16) _Float16 xh[2 * XREG];   // 11520 B

  const int lane = threadIdx.x & 63, wid = threadIdx.x >> 6;
  const int l15 = lane & 15, hk = lane >> 4;
  const int bb = blockIdx.x * 2 + wid;
  if (bb >= nbatch) return;

  // per-lane tables: 6 + 4 coalesced dwordx4 loads, no shuffling
  union { uint4 u; f16x8 h; } cv;
  const uint4* wfp = (const uint4*)(ws + WS_WF + lane * 24);
  f16x8 wf0[2], wf1[2], wf2[2];
  cv.u = wfp[0]; wf0[0] = cv.h;
  cv.u = wfp[1]; wf1[0] = cv.h;
  cv.u = wfp[2]; wf2[0] = cv.h;
  cv.u = wfp[3]; wf0[1] = cv.h;
  cv.u = wfp[4]; wf1[1] = cv.h;
  cv.u = wfp[5]; wf2[1] = cv.h;
  const float4* cp = (const float4*)((const float*)ws + WS_CONST + lane * 16);
  const float4 c0 = cp[0], c1 = cp[1];
  const float4 h0 = cp[2], h1 = cp[3];
  const f32x4 cb0 = {c0.x, c0.y, c0.z, c0.w};
  const f32x4 cb1 = {c1.x, c1.y, c1.z, c1.w};
  const f32x4 kz  = {0.f, 0.f, 0.f, 0.f};

  // stage x: lane converts 8 contiguous elems/iter -> ds_write_b128
  _Float16* xw = &xh[wid * XREG];
  const float* xsrc = xg + (size_t)bb * (NFEAT * EMB);
#pragma unroll
  for (int it = 0; it < 5; it++) {
    int g0 = (it * 64 + lane) * 8;
    float4 a = *(const float4*)&xsrc[g0];
    float4 b = *(const float4*)&xsrc[g0 + 4];
    int row = g0 >> 6, c = g0 & 63;
    f16x8 v = {(_Float16)a.x, (_Float16)a.y, (_Float16)a.z, (_Float16)a.w,
               (_Float16)b.x, (_Float16)b.y, (_Float16)b.z, (_Float16)b.w};
    *(f16x8*)&xw[row * XH_S + c] = v;
  }
  // own-wave ds ordering handled by compiler waitcnts; no block barrier needed

  const unsigned wh = (unsigned)(wid * (XREG * 2) + hk * 16);
  float sum_e = 0.f, sum_es = 0.f;

  auto tile = [&](unsigned pij, bool full) {
    const unsigned offi = (pij & 0xFFFFu) + wh;
    const unsigned offj = (pij >> 16) + wh;
    const f16x8 xi0 = *(const f16x8*)((const char*)xh + offi);
    const f16x8 xj0 = *(const f16x8*)((const char*)xh + offj);
    const f16x8 xi1 = *(const f16x8*)((const char*)xh + offi + 64);
    const f16x8 xj1 = *(const f16x8*)((const char*)xh + offj + 64);
    f16x8 af0 = xi0 * xj0;
    f16x8 af1 = xi1 * xj1;
    f32x4 a0 = __builtin_amdgcn_mfma_f32_16x16x32_f16(wf0[0], af0, cb0, 0, 0, 0);
    f32x4 a1 = __builtin_amdgcn_mfma_f32_16x16x32_f16(wf1[0], af0, cb1, 0, 0, 0);
    f32x4 a2 = __builtin_amdgcn_mfma_f32_16x16x32_f16(wf2[0], af0, kz, 0, 0, 0);
    a0 = __builtin_amdgcn_mfma_f32_16x16x32_f16(wf0[1], af1, a0, 0, 0, 0);
    a1 = __builtin_amdgcn_mfma_f32_16x16x32_f16(wf1[1], af1, a1, 0, 0, 0);
    a2 = __builtin_amdgcn_mfma_f32_16x16x32_f16(wf2[1], af1, a2, 0, 0, 0);
    float t0 = fmaf(fmaxf(a0[0], 0.f), h0.x, fmaxf(a0[1], 0.f) * h0.y);
    float t1 = fmaf(fmaxf(a0[2], 0.f), h0.z, fmaxf(a0[3], 0.f) * h0.w);
    float t2 = fmaf(fmaxf(a1[0], 0.f), h1.x, fmaxf(a1[1], 0.f) * h1.y);
    float t3 = fmaf(fmaxf(a1[2], 0.f), h1.z, fmaxf(a1[3], 0.f) * h1.w);
    float v = xgroup_sum((t0 + t1) + (t2 + t3));
    float e = exp2f(v);                    // h pre-scaled by log2(e)
    if (!full) e = (l15 < 12) ? e : 0.f;   // pairs 780..783 pad
    sum_e += e;
    sum_es = fmaf(e, a2[0], sum_es);       // a2[0]==0 unless hk==0
  };

  u32x2 pp = *(const u32x2*)(ws + WS_PRT + l15 * 2);   // tile-pair 0 (L1-hot)
#pragma unroll 4
  for (int k = 0; k < 24; ++k) {
    const unsigned pij0 = pp[0], pij1 = pp[1];
    if (k < 23) pp = *(const u32x2*)(ws + WS_PRT + (k + 1) * 32 + l15 * 2);
    tile(pij0, true);
    tile(pij1, true);
  }
  tile(ws[WS_PRT + 24 * 32 + l15 * 2], false);         // tile 48

  sum_e  = rowsum16(sum_e);    // row 0 holds each pair exactly once
  sum_es = rowsum16(sum_es);
  if (lane == 0) outg[bb] = sum_es / sum_e;
}

extern "C" void kernel_launch(void* const* d_in, const int* in_sizes, int n_in,
                              void* d_out, int out_size, void* d_ws, size_t ws_size,
                              hipStream_t stream) {
  const float* xg = (const float*)d_in[0];
  const float* Wg = (const float*)d_in[1];
  const float* bg = (const float*)d_in[2];
  const float* hg = (const float*)d_in[3];
  const float* pg = (const float*)d_in[4];
  float* outg = (float*)d_out;
  unsigned* ws = (unsigned*)d_ws;          // uses 20 KB of d_ws
  const int Bn = in_sizes[0] / (NFEAT * EMB);
  afm_pre<<<dim3(3), dim3(256), 0, stream>>>(Wg, bg, hg, pg, ws);
  afm_kernel<<<dim3((Bn + 1) / 2), dim3(128), 0, stream>>>(xg, ws, outg, Bn);
}

// Round 15
// 41.194 us; speedup vs baseline: 1.0045x; 1.0045x over previous
//
#include <hip/hip_runtime.h>

#define NFEAT 40
#define EMB   64
#define ATT   32
#define NPAIR 780
#define NTILE 49
#define XH_S  72                 // fp16 x LDS stride (elems) -> 144 B rows
#define XREG  (NFEAT * XH_S)     // 2880 elems = 5760 B

// d_ws layout (u32 units): [0,800) packed pair table, [1024,2560) W-frags
// (24 u32/lane), [4096,5120) per-lane f32 consts {cb0,cb1,h0*l2e,h1*l2e}
#define WS_PRT   0
#define WS_WF    1024
#define WS_CONST 4096

typedef __attribute__((ext_vector_type(8))) _Float16 f16x8;
typedef __attribute__((ext_vector_type(4))) float    f32x4;
typedef __attribute__((ext_vector_type(2))) unsigned u32x2;

template <int CTRL>
__device__ __forceinline__ float dpp_add_f(float v) {
  int t = __builtin_amdgcn_update_dpp(0, __float_as_int(v), CTRL, 0xF, 0xF, true);
  return v + __int_as_float(t);
}
__device__ __forceinline__ float rowsum16(float v) {
  v = dpp_add_f<0x128>(v);
  v = dpp_add_f<0x124>(v);
  v = dpp_add_f<0x122>(v);
  v = dpp_add_f<0x121>(v);
  return v;
}
__device__ __forceinline__ float xgroup_sum(float v) {
#if __has_builtin(__builtin_amdgcn_permlane16_swap) && __has_builtin(__builtin_amdgcn_permlane32_swap)
  {
    auto a = __builtin_amdgcn_permlane16_swap(__float_as_uint(v), __float_as_uint(v), false, false);
    v = __uint_as_float(a[0]) + __uint_as_float(a[1]);
    auto b = __builtin_amdgcn_permlane32_swap(__float_as_uint(v), __float_as_uint(v), false, false);
    v = __uint_as_float(b[0]) + __uint_as_float(b[1]);
  }
#else
  v += __shfl_xor(v, 16, 64);
  v += __shfl_xor(v, 32, 64);
#endif
  return v;
}
__device__ __forceinline__ int pair_off(int i) { return 39 * i - (i * (i - 1)) / 2; }

// ---------------- precompute kernel: fills d_ws once per launch ----------------
extern "C" __global__ __launch_bounds__(256)
void afm_pre(const float* __restrict__ Wg, const float* __restrict__ bg,
             const float* __restrict__ hg, const float* __restrict__ pg,
             unsigned* __restrict__ ws) {
  __shared__ float Wl[EMB * ATT];
  const int tid = threadIdx.x;
  const float L2E = 1.4426950408889634f;

  if (blockIdx.x == 0) {            // W fragments
    for (int f = tid; f < EMB * ATT / 4; f += 256)
      *(float4*)&Wl[f * 4] = ((const float4*)Wg)[f];
    __syncthreads();
    for (int o = tid; o < 1536; o += 256) {
      int lane = o / 24, rem = o % 24, frag = rem >> 2, pi = rem & 3;
      int kk = frag / 3, which = frag % 3;
      int l15 = lane & 15, hk = lane >> 4;
      unsigned out = 0;
#pragma unroll
      for (int s = 0; s < 2; s++) {
        int t = pi * 2 + s;
        int krow = kk * 32 + hk * 8 + t;
        float v = (which == 0) ? Wl[krow * ATT + l15]
                : (which == 1) ? Wl[krow * ATT + 16 + l15]
                               : ((l15 == 0) ? pg[krow] : 0.f);
        _Float16 hv = (_Float16)v;
        unsigned short bits = __builtin_bit_cast(unsigned short, hv);
        out |= (unsigned)bits << (16 * s);
      }
      ws[WS_WF + lane * 24 + rem] = out;
    }
  } else if (blockIdx.x == 1) {     // packed pair table
    for (int p = tid; p < NTILE * 16; p += 256) {
      int i = 0, j = 0;
      if (p < NPAIR) {
        i = (int)((79.0f - sqrtf(6241.0f - 8.0f * (float)p)) * 0.5f);
        if (i < 0) i = 0;
        while (pair_off(i + 1) <= p) ++i;
        while (pair_off(i) > p) --i;
        j = i + 1 + (p - pair_off(i));
      }
      int t = p >> 4, l = p & 15;
      ws[WS_PRT + (t >> 1) * 32 + l * 2 + (t & 1)] =
          (unsigned)(i * 144) | ((unsigned)(j * 144) << 16);
    }
  } else if (blockIdx.x == 2) {     // per-lane bias/h consts
    for (int o = tid; o < 1024; o += 256) {
      int lane = o >> 4, r = o & 15;
      int hk = lane >> 4, g = r >> 2, e = r & 3;
      float v;
      if (g == 0)      v = bg[hk * 4 + e];
      else if (g == 1) v = bg[16 + hk * 4 + e];
      else if (g == 2) v = hg[hk * 4 + e] * L2E;
      else             v = hg[16 + hk * 4 + e] * L2E;
      ((float*)ws)[WS_CONST + o] = v;
    }
  }
}

// -------- main kernel: 1 wave = 1 batch, 4096 blocks, no barriers --------
extern "C" __global__ __launch_bounds__(64)
void afm_kernel(const float* __restrict__ xg, const unsigned* __restrict__ ws,
                float* __restrict__ outg) {
  __shared__ __align__(16) _Float16 xh[XREG];   // 5760 B

  const int lane = threadIdx.x;
  const int l15 = lane & 15, hk = lane >> 4;
  const int bb = blockIdx.x;

  // per-lane tables: 10 coalesced dwordx4 loads
  union { uint4 u; f16x8 h; } cv;
  const uint4* wfp = (const uint4*)(ws + WS_WF + lane * 24);
  f16x8 wf0[2], wf1[2], wf2[2];
  cv.u = wfp[0]; wf0[0] = cv.h;
  cv.u = wfp[1]; wf1[0] = cv.h;
  cv.u = wfp[2]; wf2[0] = cv.h;
  cv.u = wfp[3]; wf0[1] = cv.h;
  cv.u = wfp[4]; wf1[1] = cv.h;
  cv.u = wfp[5]; wf2[1] = cv.h;
  const float4* cp = (const float4*)((const float*)ws + WS_CONST + lane * 16);
  const float4 c0 = cp[0], c1 = cp[1];
  const float4 h0 = cp[2], h1 = cp[3];
  const f32x4 cb0 = {c0.x, c0.y, c0.z, c0.w};
  const f32x4 cb1 = {c1.x, c1.y, c1.z, c1.w};
  const f32x4 kz  = {0.f, 0.f, 0.f, 0.f};

  // stage x: lane converts 8 contiguous elems/iter -> ds_write_b128
  const float* xsrc = xg + (size_t)bb * (NFEAT * EMB);
#pragma unroll
  for (int it = 0; it < 5; it++) {
    int g0 = (it * 64 + lane) * 8;
    float4 a = *(const float4*)&xsrc[g0];
    float4 b = *(const float4*)&xsrc[g0 + 4];
    int row = g0 >> 6, c = g0 & 63;
    f16x8 v = {(_Float16)a.x, (_Float16)a.y, (_Float16)a.z, (_Float16)a.w,
               (_Float16)b.x, (_Float16)b.y, (_Float16)b.z, (_Float16)b.w};
    *(f16x8*)&xh[row * XH_S + c] = v;
  }
  // single wave: program order + compiler waitcnts give write->read safety

  const unsigned wh = (unsigned)(hk * 16);
  float sum_e = 0.f, sum_es = 0.f;

  auto tile = [&](unsigned pij, bool full) {
    const unsigned offi = (pij & 0xFFFFu) + wh;
    const unsigned offj = (pij >> 16) + wh;
    const f16x8 xi0 = *(const f16x8*)((const char*)xh + offi);
    const f16x8 xj0 = *(const f16x8*)((const char*)xh + offj);
    const f16x8 xi1 = *(const f16x8*)((const char*)xh + offi + 64);
    const f16x8 xj1 = *(const f16x8*)((const char*)xh + offj + 64);
    f16x8 af0 = xi0 * xj0;
    f16x8 af1 = xi1 * xj1;
    f32x4 a0 = __builtin_amdgcn_mfma_f32_16x16x32_f16(wf0[0], af0, cb0, 0, 0, 0);
    f32x4 a1 = __builtin_amdgcn_mfma_f32_16x16x32_f16(wf1[0], af0, cb1, 0, 0, 0);
    f32x4 a2 = __builtin_amdgcn_mfma_f32_16x16x32_f16(wf2[0], af0, kz, 0, 0, 0);
    a0 = __builtin_amdgcn_mfma_f32_16x16x32_f16(wf0[1], af1, a0, 0, 0, 0);
    a1 = __builtin_amdgcn_mfma_f32_16x16x32_f16(wf1[1], af1, a1, 0, 0, 0);
    a2 = __builtin_amdgcn_mfma_f32_16x16x32_f16(wf2[1], af1, a2, 0, 0, 0);
    float t0 = fmaf(fmaxf(a0[0], 0.f), h0.x, fmaxf(a0[1], 0.f) * h0.y);
    float t1 = fmaf(fmaxf(a0[2], 0.f), h0.z, fmaxf(a0[3], 0.f) * h0.w);
    float t2 = fmaf(fmaxf(a1[0], 0.f), h1.x, fmaxf(a1[1], 0.f) * h1.y);
    float t3 = fmaf(fmaxf(a1[2], 0.f), h1.z, fmaxf(a1[3], 0.f) * h1.w);
    float v = xgroup_sum((t0 + t1) + (t2 + t3));
    float e = exp2f(v);                    // h pre-scaled by log2(e)
    if (!full) e = (l15 < 12) ? e : 0.f;   // pairs 780..783 pad
    sum_e += e;
    sum_es = fmaf(e, a2[0], sum_es);       // a2[0]==0 unless hk==0
  };

  u32x2 pp = *(const u32x2*)(ws + WS_PRT + l15 * 2);   // tile-pair 0
#pragma unroll 4
  for (int k = 0; k < 24; ++k) {
    const unsigned pij0 = pp[0], pij1 = pp[1];
    if (k < 23) pp = *(const u32x2*)(ws + WS_PRT + (k + 1) * 32 + l15 * 2);
    tile(pij0, true);
    tile(pij1, true);
  }
  tile(ws[WS_PRT + 24 * 32 + l15 * 2], false);         // tile 48

  sum_e  = rowsum16(sum_e);    // row 0 holds each pair exactly once
  sum_es = rowsum16(sum_es);
  if (lane == 0) outg[bb] = sum_es / sum_e;
}

extern "C" void kernel_launch(void* const* d_in, const int* in_sizes, int n_in,
                              void* d_out, int out_size, void* d_ws, size_t ws_size,
                              hipStream_t stream) {
  const float* xg = (const float*)d_in[0];
  const float* Wg = (const float*)d_in[1];
  const float* bg = (const float*)d_in[2];
  const float* hg = (const float*)d_in[3];
  const float* pg = (const float*)d_in[4];
  float* outg = (float*)d_out;
  unsigned* ws = (unsigned*)d_ws;
  const int Bn = in_sizes[0] / (NFEAT * EMB);
  afm_pre<<<dim3(3), dim3(256), 0, stream>>>(Wg, bg, hg, pg, ws);
  afm_kernel<<<dim3(Bn), dim3(64), 0, stream>>>(xg, ws, outg);
}